// Round 1
// baseline (359.770 us; speedup 1.0000x reference)
//
#include <hip/hip_runtime.h>
#include <math.h>

#define HH 96
#define WW 96
#define HW 9216
#define CIN 128
#define COUT 256

typedef _Float16 f16;
typedef _Float16 f16x2 __attribute__((ext_vector_type(2)));
typedef _Float16 f16x8 __attribute__((ext_vector_type(8)));
typedef __attribute__((ext_vector_type(4))) float f32x4;

static __device__ __forceinline__ unsigned short f2h(float f) {
  union { f16 h; unsigned short u; } v; v.h = (f16)f; return v.u;
}

// ---------------- prep kernels ----------------

// x NCHW fp32 -> xTh NHWC f16
__global__ __launch_bounds__(256) void k_xtb(const float* __restrict__ x,
                                             unsigned short* __restrict__ xTh) {
  __shared__ float tile[32][129];
  int bid = blockIdx.x;             // b*288 + h*3 + wseg
  int wseg = bid % 3, h = (bid / 3) % 96, b = bid / 288;
  int t = threadIdx.x;
  int wl = t & 31, cg = t >> 5;
  const float* xp = x + ((size_t)(b * 128 + cg) * 96 + h) * 96 + wseg * 32 + wl;
#pragma unroll
  for (int i = 0; i < 16; ++i)
    tile[wl][cg + 8 * i] = xp[(size_t)8 * i * HW];
  __syncthreads();
  int cl = t & 127, wg = t >> 7;
  unsigned short* op = xTh + (((size_t)(b * 96 + h) * 96) + wseg * 32) * 128 + cl;
#pragma unroll
  for (int i = 0; i < 16; ++i)
    op[(size_t)(wg + 2 * i) * 128] = f2h(tile[wg + 2 * i][cl]);
}

// wAbF: MFMA-fragment-ordered offset/mask weights, f16.
// index = ((kpos*2 + n16)*4 + ks)*512 + lane*8 + j
// n = n16*16 + (lane&15); c = ks*32 + (lane>>4)*8 + j
__global__ void k_wab(unsigned short* __restrict__ wAbF, const float* __restrict__ offw,
                      const float* __restrict__ modw) {
  int i = blockIdx.x * 256 + threadIdx.x;
  if (i >= 9 * 2 * 4 * 512) return;
  int j = i & 7;
  int l = (i >> 3) & 63;
  int ks = (i >> 9) & 3;
  int ng = i >> 11;                 // kpos*2 + n16
  int kpos = ng >> 1, n16 = ng & 1;
  int n = n16 * 16 + (l & 15);
  int c = ks * 32 + (l >> 4) * 8 + j;
  float v = 0.f;
  if (n < 18) v = offw[n * 1152 + c * 9 + kpos];
  else if (n < 27) v = modw[(n - 18) * 1152 + c * 9 + kpos];
  wAbF[i] = f2h(v);
}

// wTtF: MFMA-fragment-ordered main weights, f16.
// index = ((kpos*16 + n16)*4 + ks)*512 + lane*8 + j
__global__ void k_wtb(unsigned short* __restrict__ wTtF, const float* __restrict__ wgt) {
  int i = blockIdx.x * 256 + threadIdx.x;
  if (i >= 9 * 16 * 4 * 512) return;
  int j = i & 7;
  int l = (i >> 3) & 63;
  int ks = (i >> 9) & 3;
  int ng = i >> 11;                 // kpos*16 + n16
  int kpos = ng >> 4, n16 = ng & 15;
  int n = n16 * 16 + (l & 15);
  int c = ks * 32 + (l >> 4) * 8 + j;
  wTtF[i] = f2h(wgt[n * 1152 + c * 9 + kpos]);
}

// ---------------- offset/mask conv: barrier-free MFMA ----------------
// 576 blocks x 256 thr. Wave owns 16 px, all N=32. A direct from global (f16),
// B from wAbF fragment layout. LDS only for per-wave epilogue transpose.
__global__ __launch_bounds__(256, 6) void k_offconv(const unsigned short* __restrict__ xTh,
                                                    const unsigned short* __restrict__ wAbF,
                                                    const float* __restrict__ offb,
                                                    const float* __restrict__ modb,
                                                    float* __restrict__ om) {
  __shared__ float ez[4 * 528];     // 4 waves x [16][33]
  int t = threadIdx.x;
  int l = t & 63, w = t >> 6;
  int lm = l & 15, lq = l >> 4;
  int raw = blockIdx.x;
  int bid = (raw & 7) * 72 + (raw >> 3);   // XCD swizzle (576 = 8*72)
  int pix0 = bid * 64;
  int b = pix0 / HW;
  int posim0 = pix0 % HW;
  int prow = pix0 + w * 16 + lm;
  int pim = prow % HW;
  int ho = pim / 96, wo = pim % 96;

  f32x4 acc[2];
  acc[0] = (f32x4){0.f, 0.f, 0.f, 0.f};
  acc[1] = (f32x4){0.f, 0.f, 0.f, 0.f};
  const f16x8 zv = {0, 0, 0, 0, 0, 0, 0, 0};

#pragma unroll 1
  for (int kpos = 0; kpos < 9; ++kpos) {
    int dyr = kpos / 3 - 1, dxr = kpos % 3 - 1;
    bool valid = ((unsigned)(ho + dyr) < 96u) && ((unsigned)(wo + dxr) < 96u);
    int srow = valid ? (prow + dyr * 96 + dxr) : prow;
    const unsigned short* ap = xTh + (size_t)srow * 128 + lq * 8;
    const unsigned short* bp = wAbF + (size_t)(kpos * 8) * 512 + l * 8;
#pragma unroll
    for (int ks = 0; ks < 4; ++ks) {
      f16x8 af = valid ? *(const f16x8*)(ap + ks * 32) : zv;
      f16x8 bf0 = *(const f16x8*)(bp + (size_t)ks * 512);
      f16x8 bf1 = *(const f16x8*)(bp + (size_t)(4 + ks) * 512);
      acc[0] = __builtin_amdgcn_mfma_f32_16x16x32_f16(af, bf0, acc[0], 0, 0, 0);
      acc[1] = __builtin_amdgcn_mfma_f32_16x16x32_f16(af, bf1, acc[1], 0, 0, 0);
    }
  }

  // epilogue: per-wave zone, no barriers (wave-internal lgkmcnt ordering)
  float* z = ez + w * 528;
#pragma unroll
  for (int nt = 0; nt < 2; ++nt)
#pragma unroll
    for (int r = 0; r < 4; ++r)
      z[(lq * 4 + r) * 33 + nt * 16 + lm] = acc[nt][r];
#pragma unroll
  for (int j = 0; j < 7; ++j) {
    int n = j * 4 + lq;
    if (n < 27) {
      float v = z[lm * 33 + n];
      if (n < 18) {
        v += offb[n];
      } else {
        v += modb[n - 18];
        v = 1.f / (1.f + expf(-v));
      }
      om[((size_t)b * 27 + n) * HW + posim0 + w * 16 + lm] = v;
    }
  }
}

// ---------------- main deformable conv: barrier-free MFMA ----------------
// 1152 blocks x 256 thr. M-tile 32 px, N=256 (wave owns 64), K = 9 taps x 128c.
// A fragment computed per-lane: 4-corner f16 gather + v_pk_fma_f16 bilinear blend.
// B direct-to-register from fragment-ordered wTtF. Zero __syncthreads.
__global__ __launch_bounds__(256, 3) void k_mfma(const unsigned short* __restrict__ xTh,
                                                 const unsigned short* __restrict__ wTtF,
                                                 const float* __restrict__ bias,
                                                 const float* __restrict__ om,
                                                 float* __restrict__ out) {
  __shared__ float ez[4 * 544];     // 4 waves x [32][17]
  int t = threadIdx.x;
  int l = t & 63, w = t >> 6;
  int lm = l & 15, lq = l >> 4;
  int raw = blockIdx.x;
  int bid = (raw & 7) * 144 + (raw >> 3);  // XCD swizzle (1152 = 8*144)
  int pix0 = bid * 32;
  int b = pix0 / HW;
  int posim0 = pix0 % HW;

  const float* omb = om + (size_t)b * 27 * HW;
  int ibase = b * HW;

  int pim[2], ho[2], wo[2];
#pragma unroll
  for (int mt = 0; mt < 2; ++mt) {
    int prow = pix0 + mt * 16 + lm;
    pim[mt] = prow % HW;
    ho[mt] = pim[mt] / 96;
    wo[mt] = pim[mt] % 96;
  }

  f32x4 acc[2][4];
#pragma unroll
  for (int i = 0; i < 2; ++i)
#pragma unroll
    for (int j = 0; j < 4; ++j)
      acc[i][j] = (f32x4){0.f, 0.f, 0.f, 0.f};

#pragma unroll 1
  for (int kpos = 0; kpos < 9; ++kpos) {
    int o00[2], o01[2], o10[2], o11[2];
    f16x2 w00p[2], w01p[2], w10p[2], w11p[2];
#pragma unroll
    for (int mt = 0; mt < 2; ++mt) {
      float dy = omb[(size_t)(2 * kpos) * HW + pim[mt]];
      float dx = omb[(size_t)(2 * kpos + 1) * HW + pim[mt]];
      float mk = omb[(size_t)(18 + kpos) * HW + pim[mt]];
      float py = (float)(ho[mt] - 1 + kpos / 3) + dy;
      float pxf = (float)(wo[mt] - 1 + kpos % 3) + dx;
      float fy = floorf(py), fx = floorf(pxf);
      int y0 = (int)fy, x0 = (int)fx;
      float ly = py - fy, lx = pxf - fx;
      float w00 = (1.f - ly) * (1.f - lx), w01 = (1.f - ly) * lx;
      float w10 = ly * (1.f - lx),         w11 = ly * lx;
      bool vy0 = (unsigned)y0 < 96u, vy1 = (unsigned)(y0 + 1) < 96u;
      bool vx0 = (unsigned)x0 < 96u, vx1 = (unsigned)(x0 + 1) < 96u;
      w00 = (vy0 && vx0) ? w00 * mk : 0.f;
      w01 = (vy0 && vx1) ? w01 * mk : 0.f;
      w10 = (vy1 && vx0) ? w10 * mk : 0.f;
      w11 = (vy1 && vx1) ? w11 * mk : 0.f;
      int y0c = min(max(y0, 0), 95), y1c = min(max(y0 + 1, 0), 95);
      int x0c = min(max(x0, 0), 95), x1c = min(max(x0 + 1, 0), 95);
      o00[mt] = (ibase + y0c * 96 + x0c) * 128 + lq * 8;
      o01[mt] = (ibase + y0c * 96 + x1c) * 128 + lq * 8;
      o10[mt] = (ibase + y1c * 96 + x0c) * 128 + lq * 8;
      o11[mt] = (ibase + y1c * 96 + x1c) * 128 + lq * 8;
      f16 h00 = (f16)w00, h01 = (f16)w01, h10 = (f16)w10, h11 = (f16)w11;
      w00p[mt] = (f16x2){h00, h00};
      w01p[mt] = (f16x2){h01, h01};
      w10p[mt] = (f16x2){h10, h10};
      w11p[mt] = (f16x2){h11, h11};
    }
    const unsigned short* bp = wTtF + (size_t)((kpos * 16 + w * 4) * 4) * 512 + l * 8;
#pragma unroll
    for (int ks = 0; ks < 4; ++ks) {
      f16x8 af[2];
#pragma unroll
      for (int mt = 0; mt < 2; ++mt) {
        int c = ks * 32;
        union { uint4 u; f16x2 h[4]; } q0, q1, q2, q3;
        q0.u = *(const uint4*)(xTh + o00[mt] + c);
        q1.u = *(const uint4*)(xTh + o01[mt] + c);
        q2.u = *(const uint4*)(xTh + o10[mt] + c);
        q3.u = *(const uint4*)(xTh + o11[mt] + c);
        union { f16x8 v; f16x2 h[4]; } r;
#pragma unroll
        for (int j = 0; j < 4; ++j)
          r.h[j] = q0.h[j] * w00p[mt] + q1.h[j] * w01p[mt] +
                   q2.h[j] * w10p[mt] + q3.h[j] * w11p[mt];
        af[mt] = r.v;
      }
#pragma unroll
      for (int nt = 0; nt < 4; ++nt) {
        f16x8 bf = *(const f16x8*)(bp + (size_t)(nt * 4 + ks) * 512);
        acc[0][nt] = __builtin_amdgcn_mfma_f32_16x16x32_f16(af[0], bf, acc[0][nt], 0, 0, 0);
        acc[1][nt] = __builtin_amdgcn_mfma_f32_16x16x32_f16(af[1], bf, acc[1][nt], 0, 0, 0);
      }
    }
  }

  // epilogue: per-wave LDS transpose -> coalesced stores (no barriers needed)
  float bias_v[4];
#pragma unroll
  for (int nt = 0; nt < 4; ++nt) bias_v[nt] = bias[w * 64 + nt * 16 + lm];
  float* z = ez + w * 544;
#pragma unroll
  for (int nt = 0; nt < 4; ++nt) {
#pragma unroll
    for (int mt = 0; mt < 2; ++mt)
#pragma unroll
      for (int r = 0; r < 4; ++r)
        z[(mt * 16 + lq * 4 + r) * 17 + lm] = acc[mt][nt][r] + bias_v[nt];
    float* ob = out + ((size_t)(b * COUT + w * 64 + nt * 16)) * HW + posim0;
#pragma unroll
    for (int j = 0; j < 8; ++j) {
      int n = j * 2 + (l >> 5);
      int px = l & 31;
      ob[(size_t)n * HW + px] = z[px * 17 + n];
    }
  }
}

extern "C" void kernel_launch(void* const* d_in, const int* in_sizes, int n_in,
                              void* d_out, int out_size, void* d_ws, size_t ws_size,
                              hipStream_t stream) {
  const float* x      = (const float*)d_in[0];
  const float* weight = (const float*)d_in[1];
  const float* bias   = (const float*)d_in[2];
  const float* offw   = (const float*)d_in[3];
  const float* offb   = (const float*)d_in[4];
  const float* modw   = (const float*)d_in[5];
  const float* modb   = (const float*)d_in[6];
  float* out = (float*)d_out;
  float* ws = (float*)d_ws;

  float* offmask = ws;                                        // 995328 f
  unsigned short* xTh = (unsigned short*)(ws + 995328);       // 4718592 us
  unsigned short* wTtF = (unsigned short*)(ws + 995328 + 2359296);           // 294912 us
  unsigned short* wAbF = (unsigned short*)(ws + 995328 + 2359296 + 147456);  // 36864 us

  k_xtb<<<1152, 256, 0, stream>>>(x, xTh);
  k_wab<<<144, 256, 0, stream>>>(wAbF, offw, modw);
  k_wtb<<<1152, 256, 0, stream>>>(wTtF, weight);
  k_offconv<<<576, 256, 0, stream>>>(xTh, wAbF, offb, modb, offmask);
  k_mfma<<<1152, 256, 0, stream>>>(xTh, wTtF, bias, offmask, out);
}

// Round 4
// 189.325 us; speedup vs baseline: 1.9003x; 1.9003x over previous
//
#include <hip/hip_runtime.h>
#include <math.h>

#define HH 96
#define WW 96
#define HW 9216
#define CIN 128
#define COUT 256

typedef _Float16 f16;
typedef _Float16 f16x2 __attribute__((ext_vector_type(2)));
typedef _Float16 f16x8 __attribute__((ext_vector_type(8)));
typedef __attribute__((ext_vector_type(4))) float f32x4;

static __device__ __forceinline__ unsigned short f2h(float f) {
  union { f16 h; unsigned short u; } v; v.h = (f16)f; return v.u;
}

// ---------------- prep kernels ----------------

// x NCHW fp32 -> xTh NHWC f16
__global__ __launch_bounds__(256) void k_xtb(const float* __restrict__ x,
                                             unsigned short* __restrict__ xTh) {
  __shared__ float tile[32][129];
  int bid = blockIdx.x;             // b*288 + h*3 + wseg
  int wseg = bid % 3, h = (bid / 3) % 96, b = bid / 288;
  int t = threadIdx.x;
  int wl = t & 31, cg = t >> 5;
  const float* xp = x + ((size_t)(b * 128 + cg) * 96 + h) * 96 + wseg * 32 + wl;
#pragma unroll
  for (int i = 0; i < 16; ++i)
    tile[wl][cg + 8 * i] = xp[(size_t)8 * i * HW];
  __syncthreads();
  int cl = t & 127, wg = t >> 7;
  unsigned short* op = xTh + (((size_t)(b * 96 + h) * 96) + wseg * 32) * 128 + cl;
#pragma unroll
  for (int i = 0; i < 16; ++i)
    op[(size_t)(wg + 2 * i) * 128] = f2h(tile[wg + 2 * i][cl]);
}

// wAbF: MFMA-fragment-ordered offset/mask weights, f16.
// index = ((kpos*2 + n16)*4 + ks)*512 + lane*8 + j
__global__ void k_wab(unsigned short* __restrict__ wAbF, const float* __restrict__ offw,
                      const float* __restrict__ modw) {
  int i = blockIdx.x * 256 + threadIdx.x;
  if (i >= 9 * 2 * 4 * 512) return;
  int j = i & 7;
  int l = (i >> 3) & 63;
  int ks = (i >> 9) & 3;
  int ng = i >> 11;                 // kpos*2 + n16
  int kpos = ng >> 1, n16 = ng & 1;
  int n = n16 * 16 + (l & 15);
  int c = ks * 32 + (l >> 4) * 8 + j;
  float v = 0.f;
  if (n < 18) v = offw[n * 1152 + c * 9 + kpos];
  else if (n < 27) v = modw[(n - 18) * 1152 + c * 9 + kpos];
  wAbF[i] = f2h(v);
}

// wTtF: MFMA-fragment-ordered main weights, f16.
// index = ((kpos*16 + n16)*4 + ks)*512 + lane*8 + j
__global__ void k_wtb(unsigned short* __restrict__ wTtF, const float* __restrict__ wgt) {
  int i = blockIdx.x * 256 + threadIdx.x;
  if (i >= 9 * 16 * 4 * 512) return;
  int j = i & 7;
  int l = (i >> 3) & 63;
  int ks = (i >> 9) & 3;
  int ng = i >> 11;                 // kpos*16 + n16
  int kpos = ng >> 4, n16 = ng & 15;
  int n = n16 * 16 + (l & 15);
  int c = ks * 32 + (l >> 4) * 8 + j;
  wTtF[i] = f2h(wgt[n * 1152 + c * 9 + kpos]);
}

// ---------------- offset/mask conv: barrier-free MFMA (ran + refcheck'd in R1) ----------------
__global__ __launch_bounds__(256, 6) void k_offconv(const unsigned short* __restrict__ xTh,
                                                    const unsigned short* __restrict__ wAbF,
                                                    const float* __restrict__ offb,
                                                    const float* __restrict__ modb,
                                                    float* __restrict__ om) {
  __shared__ float ez[4 * 528];     // 4 waves x [16][33]
  int t = threadIdx.x;
  int l = t & 63, w = t >> 6;
  int lm = l & 15, lq = l >> 4;
  int raw = blockIdx.x;
  int bid = (raw & 7) * 72 + (raw >> 3);   // XCD swizzle (576 = 8*72)
  int pix0 = bid * 64;
  int b = pix0 / HW;
  int posim0 = pix0 % HW;
  int prow = pix0 + w * 16 + lm;
  int pim = prow % HW;
  int ho = pim / 96, wo = pim % 96;

  f32x4 acc[2];
  acc[0] = (f32x4){0.f, 0.f, 0.f, 0.f};
  acc[1] = (f32x4){0.f, 0.f, 0.f, 0.f};
  const f16x8 zv = {0, 0, 0, 0, 0, 0, 0, 0};

#pragma unroll 1
  for (int kpos = 0; kpos < 9; ++kpos) {
    int dyr = kpos / 3 - 1, dxr = kpos % 3 - 1;
    bool valid = ((unsigned)(ho + dyr) < 96u) && ((unsigned)(wo + dxr) < 96u);
    int srow = valid ? (prow + dyr * 96 + dxr) : prow;
    const unsigned short* ap = xTh + (size_t)srow * 128 + lq * 8;
    const unsigned short* bp = wAbF + (size_t)(kpos * 8) * 512 + l * 8;
#pragma unroll
    for (int ks = 0; ks < 4; ++ks) {
      f16x8 af = valid ? *(const f16x8*)(ap + ks * 32) : zv;
      f16x8 bf0 = *(const f16x8*)(bp + (size_t)ks * 512);
      f16x8 bf1 = *(const f16x8*)(bp + (size_t)(4 + ks) * 512);
      acc[0] = __builtin_amdgcn_mfma_f32_16x16x32_f16(af, bf0, acc[0], 0, 0, 0);
      acc[1] = __builtin_amdgcn_mfma_f32_16x16x32_f16(af, bf1, acc[1], 0, 0, 0);
    }
  }

  float* z = ez + w * 528;
#pragma unroll
  for (int nt = 0; nt < 2; ++nt)
#pragma unroll
    for (int r = 0; r < 4; ++r)
      z[(lq * 4 + r) * 33 + nt * 16 + lm] = acc[nt][r];
#pragma unroll
  for (int j = 0; j < 7; ++j) {
    int n = j * 4 + lq;
    if (n < 27) {
      float v = z[lm * 33 + n];
      if (n < 18) {
        v += offb[n];
      } else {
        v += modb[n - 18];
        v = 1.f / (1.f + expf(-v));
      }
      om[((size_t)b * 27 + n) * HW + posim0 + w * 16 + lm] = v;
    }
  }
}

// ---------------- main deformable conv: round-0 control flow, two changes ----------------
// 576 blocks x 256 thr. M-tile 64 px, N=256, K = 9 taps x 2x64c.
// Change 1: B direct-to-register from fragment-ordered wTtF (no B LDS, no conflicts).
// Change 2: f16 data + v_pk_fma_f16 bilinear interp (stage VALU ~3x cheaper).
__global__ __launch_bounds__(256) void k_mfma(const unsigned short* __restrict__ xTh,
                                              const unsigned short* __restrict__ wTtF,
                                              const float* __restrict__ bias,
                                              const float* __restrict__ om,
                                              float* __restrict__ out) {
  __shared__ __align__(16) unsigned short Ab[64 * 72];   // 9216 B
  __shared__ __align__(16) float ezs[4 * 1088];          // 17408 B epilogue zones

  int t = threadIdx.x;
  int l = t & 63;
  int w = t >> 6;
  int lm = l & 15, lq = l >> 4;
  int raw = blockIdx.x;
  int bid = (raw & 7) * 72 + (raw >> 3);   // XCD swizzle (576 = 8*72)
  int pix0 = bid * 64;
  int b = pix0 / HW;
  int posim0 = pix0 % HW;

  int px = t & 63;
  int basegrp = t >> 6;
  int pos = pix0 + px;
  int ho = (pos % HW) / 96, wo = pos % 96;
  const float* omp = om + (size_t)b * 27 * HW + (pos % HW);
  int ibase = b * HW;

  f32x4 acc[4][4];
#pragma unroll
  for (int i = 0; i < 4; ++i)
#pragma unroll
    for (int j = 0; j < 4; ++j)
      acc[i][j] = (f32x4){0.f, 0.f, 0.f, 0.f};

  for (int kpos = 0; kpos < 9; ++kpos) {
    // geometry in registers (per staging pixel px)
    float dy = omp[(size_t)(2 * kpos) * HW];
    float dx = omp[(size_t)(2 * kpos + 1) * HW];
    float mk = omp[(size_t)(18 + kpos) * HW];
    float py = (float)(ho - 1 + kpos / 3) + dy;
    float pxf = (float)(wo - 1 + kpos % 3) + dx;
    float fy = floorf(py), fx = floorf(pxf);
    int y0 = (int)fy, x0 = (int)fx;
    float ly = py - fy, lx = pxf - fx;
    float w00 = (1.f - ly) * (1.f - lx), w01 = (1.f - ly) * lx;
    float w10 = ly * (1.f - lx),         w11 = ly * lx;
    bool vy0 = (unsigned)y0 < 96u, vy1 = (unsigned)(y0 + 1) < 96u;
    bool vx0 = (unsigned)x0 < 96u, vx1 = (unsigned)(x0 + 1) < 96u;
    w00 = (vy0 && vx0) ? w00 * mk : 0.f;
    w01 = (vy0 && vx1) ? w01 * mk : 0.f;
    w10 = (vy1 && vx0) ? w10 * mk : 0.f;
    w11 = (vy1 && vx1) ? w11 * mk : 0.f;
    int y0c = min(max(y0, 0), 95), y1c = min(max(y0 + 1, 0), 95);
    int x0c = min(max(x0, 0), 95), x1c = min(max(x0 + 1, 0), 95);
    int o00 = (ibase + y0c * 96 + x0c) * 128;
    int o01 = (ibase + y0c * 96 + x1c) * 128;
    int o10 = (ibase + y1c * 96 + x0c) * 128;
    int o11 = (ibase + y1c * 96 + x1c) * 128;
    f16 h00 = (f16)w00, h01 = (f16)w01, h10 = (f16)w10, h11 = (f16)w11;
    f16x2 wp00 = (f16x2){h00, h00}, wp01 = (f16x2){h01, h01};
    f16x2 wp10 = (f16x2){h10, h10}, wp11 = (f16x2){h11, h11};

#pragma unroll
    for (int half = 0; half < 2; ++half) {
      int c0 = half * 64;
      __syncthreads();
      // ---- stage A: sample 64 px x 64 c (f16 gather + packed bilinear)
#pragma unroll
      for (int item = 0; item < 2; ++item) {
        int oct = basegrp + 4 * item;
        int cc = c0 + oct * 8;
        union { uint4 u; f16x2 h[4]; } a0, a1, a2, a3;
        a0.u = *(const uint4*)(xTh + o00 + cc);
        a1.u = *(const uint4*)(xTh + o01 + cc);
        a2.u = *(const uint4*)(xTh + o10 + cc);
        a3.u = *(const uint4*)(xTh + o11 + cc);
        union { f16x8 v; f16x2 h[4]; } r;
#pragma unroll
        for (int j = 0; j < 4; ++j)
          r.h[j] = a0.h[j] * wp00 + a1.h[j] * wp01 + a2.h[j] * wp10 + a3.h[j] * wp11;
        *(f16x8*)(Ab + px * 72 + oct * 8) = r.v;
      }
      __syncthreads();
      // ---- MFMA: A from LDS, B direct from fragment-ordered global (L2)
#pragma unroll
      for (int ks = 0; ks < 2; ++ks) {
        f16x8 af[4], bfv[4];
#pragma unroll
        for (int mt = 0; mt < 4; ++mt)
          af[mt] = *(const f16x8*)(Ab + (mt * 16 + lm) * 72 + ks * 32 + lq * 8);
        const unsigned short* bp =
            wTtF + (size_t)((kpos * 16 + w * 4) * 4 + 2 * half + ks) * 512 + l * 8;
#pragma unroll
        for (int nt = 0; nt < 4; ++nt)
          bfv[nt] = *(const f16x8*)(bp + (size_t)nt * 4 * 512);
#pragma unroll
        for (int mt = 0; mt < 4; ++mt)
#pragma unroll
          for (int nt = 0; nt < 4; ++nt)
            acc[mt][nt] = __builtin_amdgcn_mfma_f32_16x16x32_f16(af[mt], bfv[nt], acc[mt][nt], 0, 0, 0);
      }
    }
  }

  // ---- epilogue: per-wave LDS transpose -> coalesced stores (round-0 pattern)
  float bias_v[4];
#pragma unroll
  for (int nt = 0; nt < 4; ++nt) bias_v[nt] = bias[w * 64 + nt * 16 + lm];
  float* ez = ezs + w * 1088;   // 64*17 floats per wave zone
#pragma unroll
  for (int nt = 0; nt < 4; ++nt) {
    __syncthreads();
#pragma unroll
    for (int mt = 0; mt < 4; ++mt)
#pragma unroll
      for (int r = 0; r < 4; ++r)
        ez[(mt * 16 + lq * 4 + r) * 17 + lm] = acc[mt][nt][r] + bias_v[nt];
    __syncthreads();
    float* ob = out + ((size_t)(b * COUT + w * 64 + nt * 16)) * HW + posim0;
#pragma unroll
    for (int j = 0; j < 16; ++j)
      ob[(size_t)j * HW + l] = ez[l * 17 + j];
  }
}

extern "C" void kernel_launch(void* const* d_in, const int* in_sizes, int n_in,
                              void* d_out, int out_size, void* d_ws, size_t ws_size,
                              hipStream_t stream) {
  const float* x      = (const float*)d_in[0];
  const float* weight = (const float*)d_in[1];
  const float* bias   = (const float*)d_in[2];
  const float* offw   = (const float*)d_in[3];
  const float* offb   = (const float*)d_in[4];
  const float* modw   = (const float*)d_in[5];
  const float* modb   = (const float*)d_in[6];
  float* out = (float*)d_out;
  float* ws = (float*)d_ws;

  float* offmask = ws;                                        // 995328 f
  unsigned short* xTh = (unsigned short*)(ws + 995328);       // 4718592 us
  unsigned short* wTtF = (unsigned short*)(ws + 995328 + 2359296);           // 294912 us
  unsigned short* wAbF = (unsigned short*)(ws + 995328 + 2359296 + 147456);  // 36864 us

  k_xtb<<<1152, 256, 0, stream>>>(x, xTh);
  k_wab<<<144, 256, 0, stream>>>(wAbF, offw, modw);
  k_wtb<<<1152, 256, 0, stream>>>(wTtF, weight);
  k_offconv<<<576, 256, 0, stream>>>(xTh, wAbF, offb, modb, offmask);
  k_mfma<<<576, 256, 0, stream>>>(xTh, wTtF, bias, offmask, out);
}

// Round 5
// 175.809 us; speedup vs baseline: 2.0464x; 1.0769x over previous
//
#include <hip/hip_runtime.h>
#include <math.h>

#define HH 96
#define WW 96
#define HW 9216
#define CIN 128
#define COUT 256

typedef _Float16 f16;
typedef _Float16 f16x2 __attribute__((ext_vector_type(2)));
typedef _Float16 f16x8 __attribute__((ext_vector_type(8)));
typedef __attribute__((ext_vector_type(4))) float f32x4;

static __device__ __forceinline__ unsigned short f2h(float f) {
  union { f16 h; unsigned short u; } v; v.h = (f16)f; return v.u;
}

// ---------------- fused prep kernel ----------------
// blocks [0,1152): x NCHW fp32 -> xTh NHWC f16
// blocks [1152,1296): wAbF fragment-ordered offset/mask weights
// blocks [1296,2448): wTtF fragment-ordered main weights
__global__ __launch_bounds__(256) void k_prep(const float* __restrict__ x,
                                              const float* __restrict__ offw,
                                              const float* __restrict__ modw,
                                              const float* __restrict__ wgt,
                                              unsigned short* __restrict__ xTh,
                                              unsigned short* __restrict__ wAbF,
                                              unsigned short* __restrict__ wTtF) {
  __shared__ float tile[32][129];
  int bid = blockIdx.x;
  int t = threadIdx.x;
  if (bid < 1152) {
    // ---- x transpose: b*288 + h*3 + wseg
    int wseg = bid % 3, h = (bid / 3) % 96, b = bid / 288;
    int wl = t & 31, cg = t >> 5;
    const float* xp = x + ((size_t)(b * 128 + cg) * 96 + h) * 96 + wseg * 32 + wl;
#pragma unroll
    for (int i = 0; i < 16; ++i)
      tile[wl][cg + 8 * i] = xp[(size_t)8 * i * HW];
    __syncthreads();
    int cl = t & 127, wg = t >> 7;
    unsigned short* op = xTh + (((size_t)(b * 96 + h) * 96) + wseg * 32) * 128 + cl;
#pragma unroll
    for (int i = 0; i < 16; ++i)
      op[(size_t)(wg + 2 * i) * 128] = f2h(tile[wg + 2 * i][cl]);
  } else if (bid < 1296) {
    // ---- wAbF: index = ((kpos*2 + n16)*4 + ks)*512 + lane*8 + j
    int i = (bid - 1152) * 256 + t;
    if (i < 9 * 2 * 4 * 512) {
      int j = i & 7;
      int l = (i >> 3) & 63;
      int ks = (i >> 9) & 3;
      int ng = i >> 11;             // kpos*2 + n16
      int kpos = ng >> 1, n16 = ng & 1;
      int n = n16 * 16 + (l & 15);
      int c = ks * 32 + (l >> 4) * 8 + j;
      float v = 0.f;
      if (n < 18) v = offw[n * 1152 + c * 9 + kpos];
      else if (n < 27) v = modw[(n - 18) * 1152 + c * 9 + kpos];
      wAbF[i] = f2h(v);
    }
  } else {
    // ---- wTtF: index = ((kpos*16 + n16)*4 + ks)*512 + lane*8 + j
    int i = (bid - 1296) * 256 + t;
    if (i < 9 * 16 * 4 * 512) {
      int j = i & 7;
      int l = (i >> 3) & 63;
      int ks = (i >> 9) & 3;
      int ng = i >> 11;             // kpos*16 + n16
      int kpos = ng >> 4, n16 = ng & 15;
      int n = n16 * 16 + (l & 15);
      int c = ks * 32 + (l >> 4) * 8 + j;
      wTtF[i] = f2h(wgt[n * 1152 + c * 9 + kpos]);
    }
  }
}

// ---------------- fused main kernel ----------------
// 1152 blocks x 256 thr (4 waves). M-tile 32 px, N=256 (wave owns 64), K=1152.
// Prologue: offset/mask conv for own 32 px (MFMA, om -> LDS).
// Main: A gather+f16 interp staged in LDS per 64c half; B direct-to-reg from
// fragment-ordered wTtF (L2-resident). Round-4 control flow (2 barriers/half).
__global__ __launch_bounds__(256) void k_main(const unsigned short* __restrict__ xTh,
                                              const unsigned short* __restrict__ wAbF,
                                              const unsigned short* __restrict__ wTtF,
                                              const float* __restrict__ offb,
                                              const float* __restrict__ modb,
                                              const float* __restrict__ bias,
                                              float* __restrict__ out) {
  __shared__ __align__(16) unsigned short Ab[32 * 72];   // 4608 B
  __shared__ float om_lds[27 * 33];                      // 3564 B
  __shared__ float ez[4 * 1040];                         // 16640 B (wave zones 16x65)

  int t = threadIdx.x;
  int l = t & 63, w = t >> 6;
  int lm = l & 15, lq = l >> 4;
  int raw = blockIdx.x;
  int bid = (raw & 7) * 144 + (raw >> 3);   // XCD swizzle (1152 = 8*144)
  int pix0 = bid * 32;
  int b = pix0 / HW;
  int posim0 = pix0 % HW;
  int ibase = b * HW;

  // ======== offset/mask conv prologue (wave: mh = px-half, n16o = n-half) ========
  {
    int mh = w & 1, n16o = w >> 1;
    int prow = pix0 + mh * 16 + lm;
    int pimo = prow % HW;
    int hoo = pimo / 96, woo = pimo % 96;
    f32x4 acco = (f32x4){0.f, 0.f, 0.f, 0.f};
    const f16x8 zv = {0, 0, 0, 0, 0, 0, 0, 0};
#pragma unroll 1
    for (int kpos = 0; kpos < 9; ++kpos) {
      int dyr = kpos / 3 - 1, dxr = kpos % 3 - 1;
      bool valid = ((unsigned)(hoo + dyr) < 96u) && ((unsigned)(woo + dxr) < 96u);
      int srow = valid ? (prow + dyr * 96 + dxr) : prow;
      const unsigned short* ap = xTh + (size_t)srow * 128 + lq * 8;
      const unsigned short* bp = wAbF + (size_t)((kpos * 2 + n16o) * 4) * 512 + l * 8;
#pragma unroll
      for (int ks = 0; ks < 4; ++ks) {
        f16x8 af = valid ? *(const f16x8*)(ap + ks * 32) : zv;
        f16x8 bf = *(const f16x8*)(bp + (size_t)ks * 512);
        acco = __builtin_amdgcn_mfma_f32_16x16x32_f16(af, bf, acco, 0, 0, 0);
      }
    }
    // write om_lds[n][px_local], n = n16o*16+lm, px_local = mh*16 + lq*4 + r
    int n = n16o * 16 + lm;
    if (n < 27) {
      float bv = (n < 18) ? offb[n] : modb[n - 18];
#pragma unroll
      for (int r = 0; r < 4; ++r) {
        float v = acco[r] + bv;
        if (n >= 18) v = 1.f / (1.f + expf(-v));
        om_lds[n * 33 + mh * 16 + lq * 4 + r] = v;
      }
    }
  }
  __syncthreads();

  // ======== main deformable GEMM ========
  int px = t & 31;                  // staging pixel
  int oct = t >> 5;                 // staging octet 0..7 (8 channels)
  int pim = (pix0 + px) % HW;
  int ho = pim / 96, wo = pim % 96;

  f32x4 acc[2][4];
#pragma unroll
  for (int i = 0; i < 2; ++i)
#pragma unroll
    for (int j = 0; j < 4; ++j)
      acc[i][j] = (f32x4){0.f, 0.f, 0.f, 0.f};

  for (int kpos = 0; kpos < 9; ++kpos) {
    // geometry from om_lds (8x redundant across threads sharing px)
    float dy = om_lds[(2 * kpos) * 33 + px];
    float dx = om_lds[(2 * kpos + 1) * 33 + px];
    float mk = om_lds[(18 + kpos) * 33 + px];
    float py = (float)(ho - 1 + kpos / 3) + dy;
    float pxf = (float)(wo - 1 + kpos % 3) + dx;
    float fy = floorf(py), fx = floorf(pxf);
    int y0 = (int)fy, x0 = (int)fx;
    float ly = py - fy, lx = pxf - fx;
    float w00 = (1.f - ly) * (1.f - lx), w01 = (1.f - ly) * lx;
    float w10 = ly * (1.f - lx),         w11 = ly * lx;
    bool vy0 = (unsigned)y0 < 96u, vy1 = (unsigned)(y0 + 1) < 96u;
    bool vx0 = (unsigned)x0 < 96u, vx1 = (unsigned)(x0 + 1) < 96u;
    w00 = (vy0 && vx0) ? w00 * mk : 0.f;
    w01 = (vy0 && vx1) ? w01 * mk : 0.f;
    w10 = (vy1 && vx0) ? w10 * mk : 0.f;
    w11 = (vy1 && vx1) ? w11 * mk : 0.f;
    int y0c = min(max(y0, 0), 95), y1c = min(max(y0 + 1, 0), 95);
    int x0c = min(max(x0, 0), 95), x1c = min(max(x0 + 1, 0), 95);
    int o00 = (ibase + y0c * 96 + x0c) * 128;
    int o01 = (ibase + y0c * 96 + x1c) * 128;
    int o10 = (ibase + y1c * 96 + x0c) * 128;
    int o11 = (ibase + y1c * 96 + x1c) * 128;
    f16 h00 = (f16)w00, h01 = (f16)w01, h10 = (f16)w10, h11 = (f16)w11;
    f16x2 wp00 = (f16x2){h00, h00}, wp01 = (f16x2){h01, h01};
    f16x2 wp10 = (f16x2){h10, h10}, wp11 = (f16x2){h11, h11};

#pragma unroll
    for (int half = 0; half < 2; ++half) {
      int cc = half * 64 + oct * 8;
      __syncthreads();
      // ---- stage A: 32 px x 64 c (each thread: 1 octet, 4 corner loads)
      {
        union { uint4 u; f16x2 h[4]; } a0, a1, a2, a3;
        a0.u = *(const uint4*)(xTh + o00 + cc);
        a1.u = *(const uint4*)(xTh + o01 + cc);
        a2.u = *(const uint4*)(xTh + o10 + cc);
        a3.u = *(const uint4*)(xTh + o11 + cc);
        union { f16x8 v; f16x2 h[4]; } r;
#pragma unroll
        for (int j = 0; j < 4; ++j)
          r.h[j] = a0.h[j] * wp00 + a1.h[j] * wp01 + a2.h[j] * wp10 + a3.h[j] * wp11;
        *(f16x8*)(Ab + px * 72 + oct * 8) = r.v;
      }
      __syncthreads();
      // ---- MFMA: A from LDS, B direct from fragment-ordered global (L2)
#pragma unroll
      for (int ks = 0; ks < 2; ++ks) {
        f16x8 af[2], bfv[4];
#pragma unroll
        for (int mt = 0; mt < 2; ++mt)
          af[mt] = *(const f16x8*)(Ab + (mt * 16 + lm) * 72 + ks * 32 + lq * 8);
        const unsigned short* bp =
            wTtF + (size_t)((kpos * 16 + w * 4) * 4 + 2 * half + ks) * 512 + l * 8;
#pragma unroll
        for (int nt = 0; nt < 4; ++nt)
          bfv[nt] = *(const f16x8*)(bp + (size_t)nt * 4 * 512);
#pragma unroll
        for (int mt = 0; mt < 2; ++mt)
#pragma unroll
          for (int nt = 0; nt < 4; ++nt)
            acc[mt][nt] = __builtin_amdgcn_mfma_f32_16x16x32_f16(af[mt], bfv[nt], acc[mt][nt], 0, 0, 0);
      }
    }
  }

  // ======== epilogue: per-wave 16x64 transpose zones ========
  float bias_v[4];
#pragma unroll
  for (int nt = 0; nt < 4; ++nt) bias_v[nt] = bias[w * 64 + nt * 16 + lm];
  float* z = ez + w * 1040;   // [16][65]
#pragma unroll
  for (int mt = 0; mt < 2; ++mt) {
    __syncthreads();
#pragma unroll
    for (int nt = 0; nt < 4; ++nt)
#pragma unroll
      for (int r = 0; r < 4; ++r)
        z[(lq * 4 + r) * 65 + nt * 16 + lm] = acc[mt][nt][r] + bias_v[nt];
    __syncthreads();
    int pxr = l & 15;
    int nb = l >> 4;
#pragma unroll
    for (int s = 0; s < 16; ++s) {
      int n = nb + 4 * s;
      out[((size_t)(b * COUT + w * 64 + n)) * HW + posim0 + mt * 16 + pxr] = z[pxr * 65 + n];
    }
  }
}

extern "C" void kernel_launch(void* const* d_in, const int* in_sizes, int n_in,
                              void* d_out, int out_size, void* d_ws, size_t ws_size,
                              hipStream_t stream) {
  const float* x      = (const float*)d_in[0];
  const float* weight = (const float*)d_in[1];
  const float* bias   = (const float*)d_in[2];
  const float* offw   = (const float*)d_in[3];
  const float* offb   = (const float*)d_in[4];
  const float* modw   = (const float*)d_in[5];
  const float* modb   = (const float*)d_in[6];
  float* out = (float*)d_out;
  float* ws = (float*)d_ws;

  unsigned short* xTh  = (unsigned short*)ws;                      // 4718592 us
  unsigned short* wTtF = (unsigned short*)(ws + 2359296);          // 294912 us
  unsigned short* wAbF = (unsigned short*)(ws + 2359296 + 147456); // 36864 us

  k_prep<<<2448, 256, 0, stream>>>(x, offw, modw, weight, xTh, wAbF, wTtF);
  k_main<<<1152, 256, 0, stream>>>(xTh, wAbF, wTtF, offb, modb, bias, out);
}